// Round 10
// baseline (20472.787 us; speedup 1.0000x reference)
//
#include <hip/hip_runtime.h>
#include <math.h>

// ---------------------------------------------------------------------------
// UAVEnhancedModel: LSTM-with-decay + per-step LayerNorm recurrence (S=4096,
// I=512, H=1024) + uav feature path + sigmoid head.
//
//   1) gemm_xp: x_proj = x @ W_ih^T + (b_ih+b_hh), gate-interleaved xpg[s][u][g].
//   2) gemm_uf: uf = relu(uav*W1^T + b1) @ W2^T + b2          [4096, 1024]
//   3) scan: 128 blocks x 256 threads. Block b owns units j0..j0+7
//      (XCD-chunked). Thread tid owns cols 4*tid..4*tid+3 of ALL 32 block
//      gate-rows (128 W_hh*ln_g weights in VGPRs); its polled 16B of
//      hn[t-1] is exactly its FMA operand. bfly32 value-split butterfly;
//      34 floats/wave to LDS; ONE barrier; wave w finishes units 2w,2w+1
//      and publishes ONE dwordx2 (512 publish transactions/step).
//      R10 (isolated change vs R9): DOUBLE-PUMPED poll -- two outstanding
//      dwordx4 sc0 sc1 loads checked alternately at vmcnt(1) (~2x sampling
//      rate), plus EARLY first-sample issue at the end of the previous
//      iteration (first-sample latency overlaps loop tail + barrier).
//      Register-lifetime discipline (R5 crash lesson): qa/qb are loop-
//      carried with "+v" ties and a full vmcnt(0) drain holding both after
//      the reduce; no orphan loads at kernel end (skip early issue at
//      t=kS-1 + final drain).
//      Sync is DATA-FLOW: hn[] sentinel-filled; LN folded into matvec:
//      gates = xp + rstd*(acc - mu*Ar) + Br.
//   4) final: out[t] = sigmoid(ufcW @ h_ln_t + ufcb); also h_last, c_last.
// ---------------------------------------------------------------------------

constexpr int kS  = 4096;
constexpr int kI  = 512;
constexpr int kH  = 1024;
constexpr int kG4 = 4096;   // 4*kH
constexpr int kNB = 128;    // scan blocks
constexpr float kLnEps = 1e-5f;
constexpr float kWdEps = 1e-7f;
constexpr float kSent  = 1e30f;   // h clipped to [-10,10] -> unreachable

typedef float f4 __attribute__((ext_vector_type(4)));
typedef float f2 __attribute__((ext_vector_type(2)));

// ---------------- init: fill hn with sentinel ----------------
__global__ __launch_bounds__(256) void init_hn_kernel(float4* __restrict__ p) {
  const int i = blockIdx.x * 256 + threadIdx.x;   // 4096*256 float4 = S*H
  p[i] = make_float4(kSent, kSent, kSent, kSent);
}

// -------- GEMM1: xpg[s][u][g] = sum_k x[s,k]*W_ih[g*1024+u,k] + bias ------
__global__ __launch_bounds__(256) void gemm_xp_kernel(
    const float* __restrict__ A,     // x [4096,512]
    const float* __restrict__ B,     // W_ih [4096,512]
    const float* __restrict__ b_ih, const float* __restrict__ b_hh,
    float* __restrict__ C)           // xpg [4096][1024][4]
{
  __shared__ float As[32][68];
  __shared__ float Bs[32][68];
  const int bm = blockIdx.x * 64, bn = blockIdx.y * 64;
  const int tid = threadIdx.x;
  const int tx = tid & 15, ty = tid >> 4;
  float acc[4][4] = {};
  for (int k0 = 0; k0 < kI; k0 += 32) {
#pragma unroll
    for (int h = 0; h < 2; ++h) {
      const int f = tid + h * 256;
      const int row = f >> 3, c4 = (f & 7) * 4;
      const float4 a  = *(const float4*)(A + (size_t)(bm + row) * kI + k0 + c4);
      const float4 bb = *(const float4*)(B + (size_t)(bn + row) * kI + k0 + c4);
      As[c4 + 0][row] = a.x;  As[c4 + 1][row] = a.y;
      As[c4 + 2][row] = a.z;  As[c4 + 3][row] = a.w;
      Bs[c4 + 0][row] = bb.x; Bs[c4 + 1][row] = bb.y;
      Bs[c4 + 2][row] = bb.z; Bs[c4 + 3][row] = bb.w;
    }
    __syncthreads();
#pragma unroll
    for (int k = 0; k < 32; ++k) {
      const float4 a  = *(const float4*)&As[k][ty * 4];
      const float4 bb = *(const float4*)&Bs[k][tx * 4];
      const float av[4] = {a.x, a.y, a.z, a.w};
      const float bv[4] = {bb.x, bb.y, bb.z, bb.w};
#pragma unroll
      for (int i = 0; i < 4; ++i)
#pragma unroll
        for (int j = 0; j < 4; ++j) acc[i][j] += av[i] * bv[j];
    }
    __syncthreads();
  }
  const float4 bi = *(const float4*)(b_ih + bn + tx * 4);
  const float4 bh = *(const float4*)(b_hh + bn + tx * 4);
  const float bias[4] = {bi.x + bh.x, bi.y + bh.y, bi.z + bh.z, bi.w + bh.w};
  const int gate = bn >> 10;            // 64 | 1024 -> constant per block
  const int ubase = (bn & 1023) + tx * 4;
#pragma unroll
  for (int i = 0; i < 4; ++i) {
    float* dst = C + (size_t)(bm + ty * 4 + i) * kG4 + (size_t)ubase * 4 + gate;
#pragma unroll
    for (int j = 0; j < 4; ++j) dst[4 * j] = acc[i][j] + bias[j];
  }
}

// ---------------- GEMM2: uf = relu(uav*W1^T + b1) @ W2^T + b2 --------------
__global__ __launch_bounds__(256) void gemm_uf_kernel(
    const float* __restrict__ uav,
    const float* __restrict__ W1, const float* __restrict__ b1,
    const float* __restrict__ W2,
    const float* __restrict__ b2,
    float* __restrict__ C)           // uf [4096,1024]
{
  __shared__ float As[32][68];
  __shared__ float Bs[32][68];
  __shared__ float uav_s[64];
  const int bm = blockIdx.x * 64, bn = blockIdx.y * 64;
  const int tid = threadIdx.x;
  const int tx = tid & 15, ty = tid >> 4;
  if (tid < 64) uav_s[tid] = uav[bm + tid];
  __syncthreads();
  float acc[4][4] = {};
  for (int k0 = 0; k0 < kH; k0 += 32) {
#pragma unroll
    for (int h = 0; h < 2; ++h) {
      const int f = tid + h * 256;
      const int row = f >> 3, c4 = (f & 7) * 4;
      const float4 w1v = *(const float4*)(W1 + k0 + c4);
      const float4 b1v = *(const float4*)(b1 + k0 + c4);
      const float ua = uav_s[row];
      As[c4 + 0][row] = fmaxf(ua * w1v.x + b1v.x, 0.f);
      As[c4 + 1][row] = fmaxf(ua * w1v.y + b1v.y, 0.f);
      As[c4 + 2][row] = fmaxf(ua * w1v.z + b1v.z, 0.f);
      As[c4 + 3][row] = fmaxf(ua * w1v.w + b1v.w, 0.f);
      const float4 bb = *(const float4*)(W2 + (size_t)(bn + row) * kH + k0 + c4);
      Bs[c4 + 0][row] = bb.x; Bs[c4 + 1][row] = bb.y;
      Bs[c4 + 2][row] = bb.z; Bs[c4 + 3][row] = bb.w;
    }
    __syncthreads();
#pragma unroll
    for (int k = 0; k < 32; ++k) {
      const float4 a  = *(const float4*)&As[k][ty * 4];
      const float4 bb = *(const float4*)&Bs[k][tx * 4];
      const float av[4] = {a.x, a.y, a.z, a.w};
      const float bv[4] = {bb.x, bb.y, bb.z, bb.w};
#pragma unroll
      for (int i = 0; i < 4; ++i)
#pragma unroll
        for (int j = 0; j < 4; ++j) acc[i][j] += av[i] * bv[j];
    }
    __syncthreads();
  }
  const float4 b2v = *(const float4*)(b2 + bn + tx * 4);
#pragma unroll
  for (int i = 0; i < 4; ++i) {
    float4 o = make_float4(acc[i][0] + b2v.x, acc[i][1] + b2v.y,
                           acc[i][2] + b2v.z, acc[i][3] + b2v.w);
    *(float4*)(C + (size_t)(bm + ty * 4 + i) * kH + bn + tx * 4) = o;
  }
}

// ---- value-splitting butterfly: 32 per-lane partials -> every lane holds
// the wave-total of row (lane&31). 31 shfl+select+add + 1 cross-half add.
__device__ __forceinline__ void bfly32(float (&p)[32], int lane) {
#pragma unroll
  for (int k = 0; k < 16; ++k) {
    const float give = (lane & 16) ? p[k] : p[k + 16];
    const float keep = (lane & 16) ? p[k + 16] : p[k];
    p[k] = keep + __shfl_xor(give, 16, 64);
  }
#pragma unroll
  for (int k = 0; k < 8; ++k) {
    const float give = (lane & 8) ? p[k] : p[k + 8];
    const float keep = (lane & 8) ? p[k + 8] : p[k];
    p[k] = keep + __shfl_xor(give, 8, 64);
  }
#pragma unroll
  for (int k = 0; k < 4; ++k) {
    const float give = (lane & 4) ? p[k] : p[k + 4];
    const float keep = (lane & 4) ? p[k + 4] : p[k];
    p[k] = keep + __shfl_xor(give, 4, 64);
  }
#pragma unroll
  for (int k = 0; k < 2; ++k) {
    const float give = (lane & 2) ? p[k] : p[k + 2];
    const float keep = (lane & 2) ? p[k + 2] : p[k];
    p[k] = keep + __shfl_xor(give, 2, 64);
  }
  {
    const float give = (lane & 1) ? p[0] : p[1];
    const float keep = (lane & 1) ? p[1] : p[0];
    p[0] = keep + __shfl_xor(give, 1, 64);
  }
  p[0] += __shfl_xor(p[0], 32, 64);
}

// ---------------- persistent scan kernel ----------------
// Block owns 8 units j0..j0+7 (32 rows: row r <-> unit r>>2, gate r&3).
// Thread tid: cols 4*tid..4*tid+3 of all 32 rows (128 reg weights).
// Wave w finishes units 2w (lanes lr<4) and 2w+1 (lanes lr>=4), lr=lane&7.
__global__ __launch_bounds__(256, 1) void scan_kernel(
    const float* __restrict__ xpg,    // [S][H][4] ws
    const float* __restrict__ uf,     // [S,H]  ws
    float* hn,                        // [S,H]  ws (sentinel-initialized)
    const float* __restrict__ W_hh,   // [4H,H]
    const float* __restrict__ deltas, // [S]
    const float* __restrict__ Wd,     // [H]
    const float* __restrict__ ln_g,   // [H]
    const float* __restrict__ ln_b,   // [H]
    float* __restrict__ out)          // d_out (c_last slice)
{
  const int b = blockIdx.x;
  const int tid = threadIdx.x;
  const int wid = tid >> 6, lane = tid & 63;
  const int lr = lane & 7;                 // row slot within wave's 8 rows
  const int gi = lr & 3;                   // gate (i,f,g,o)
  const int uh = lr >> 2;                  // unit half (0/1)
  const int b8 = lane & ~7;
  const int j0 = (((b & 7) << 4) | (b >> 3)) << 3;   // XCD-chunked unit base
  const int unit = j0 + 2 * wid + uh;      // this lane's unit
  const int col0 = 4 * tid;                // this thread's h columns

  __shared__ float part[2][4][36];   // [buf][wave][32 rows | s1 | s2 | pad]
  __shared__ float proA[4][32], proB[4][32];

  // --- weights (scaled by ln_g) + per-row fold constants Ar, Br ---
  f4 w4[32];
  {
    float arp[32], brp[32];
    const float4 gg = *(const float4*)(ln_g + col0);
    const float4 bb = *(const float4*)(ln_b + col0);
#pragma unroll
    for (int r = 0; r < 32; ++r) {
      const int grow = (r & 3) * kH + j0 + (r >> 2);
      const float4 wv = *(const float4*)(W_hh + (size_t)grow * kH + col0);
      brp[r] = wv.x * bb.x + wv.y * bb.y + wv.z * bb.z + wv.w * bb.w;
      w4[r].x = wv.x * gg.x; w4[r].y = wv.y * gg.y;
      w4[r].z = wv.z * gg.z; w4[r].w = wv.w * gg.w;
      arp[r] = w4[r].x + w4[r].y + w4[r].z + w4[r].w;
    }
    bfly32(arp, lane);
    bfly32(brp, lane);
    if (lane < 32) { proA[wid][lane] = arp[0]; proB[wid][lane] = brp[0]; }
  }
  __syncthreads();
  const int xr = 8 * wid + lr;             // this lane's row (block-local)
  const float Ar = proA[0][xr] + proA[1][xr] + proA[2][xr] + proA[3][xr];
  const float Br = proB[0][xr] + proB[1][xr] + proB[2][xr] + proB[3][xr];

  // --- per-lane constants / pipelined operands ---
  const float wdc = fminf(fmaxf(Wd[unit], kWdEps), 10.f);
  float c_state = 0.f;
  float xp_r = xpg[(size_t)0 * kG4 + unit * 4 + gi];
  float uf_r = 1.5f * uf[(size_t)0 * kH + unit];
  float dec_r = expf(-deltas[0] * wdc);

  // loop-carried poll registers (double-pump; issued early at iter end)
  f4 qa, qb;

  for (int t = 0; t < kS; ++t) {
    const int buf = t & 1;
    if (t > 0) {
      // ---- double-pumped poll of own 16B of hn[t-1]; qa,qb already in
      // flight (issued at the end of the previous iteration). Checks
      // alternate at vmcnt(1) -> ~2x sampling rate vs drained single-load.
      const float* hp = hn + (size_t)(t - 1) * kH + col0;
      f4 q;
      for (;;) {
        asm volatile("s_waitcnt vmcnt(1)" : "+v"(qa) :: "memory");
        if (qa.x != kSent && qa.y != kSent && qa.z != kSent && qa.w != kSent) {
          q = qa; break;
        }
        asm volatile("global_load_dwordx4 %0, %1, off sc0 sc1"
                     : "=v"(qa) : "v"(hp) : "memory");
        asm volatile("s_waitcnt vmcnt(1)" : "+v"(qb) :: "memory");
        if (qb.x != kSent && qb.y != kSent && qb.z != kSent && qb.w != kSent) {
          q = qb; break;
        }
        asm volatile("global_load_dwordx4 %0, %1, off sc0 sc1"
                     : "=v"(qb) : "v"(hp) : "memory");
      }
      // ---- register FMA against own columns: 32 row partials ----
      float p[32];
#pragma unroll
      for (int r = 0; r < 32; ++r)
        p[r] = w4[r].x * q.x + w4[r].y * q.y + w4[r].z * q.z + w4[r].w * q.w;
      float s1 = q.x + q.y + q.z + q.w;
      float s2 = q.x * q.x + q.y * q.y + q.z * q.z + q.w * q.w;
      bfly32(p, lane);
#pragma unroll
      for (int d = 1; d < 64; d <<= 1) {
        s1 += __shfl_xor(s1, d, 64);
        s2 += __shfl_xor(s2, d, 64);
      }
      if (lane < 32)       part[buf][wid][lane] = p[0];
      else if (lane == 32) part[buf][wid][32] = s1;
      else if (lane == 33) part[buf][wid][33] = s2;
      // ---- drain the sibling poll load BEFORE qa/qb could be reallocated
      // (R5 lesson). Overlaps the FMA + butterfly + LDS writes above.
      asm volatile("s_waitcnt vmcnt(0)" : "+v"(qa), "+v"(qb) :: "memory");
    }
    // ---- prefetch next-step operands (after poll: vmcnt stays clean) ----
    const int tn = (t + 1 < kS) ? t + 1 : t;
    const float xp_n = xpg[(size_t)tn * kG4 + unit * 4 + gi];
    const float uf_n = uf[(size_t)tn * kH + unit];
    const float dl_n = deltas[tn];
    __syncthreads();   // single barrier per step

    float gatev = xp_r;
    if (t > 0) {
      const float acc = part[buf][0][xr] + part[buf][1][xr] +
                        part[buf][2][xr] + part[buf][3][xr];
      const float S1 = part[buf][0][32] + part[buf][1][32] +
                       part[buf][2][32] + part[buf][3][32];
      const float S2 = part[buf][0][33] + part[buf][1][33] +
                       part[buf][2][33] + part[buf][3][33];
      const float mu = S1 * (1.f / kH);
      const float var = S2 * (1.f / kH) - mu * mu;
      const float rstd = 1.f / sqrtf(var + kLnEps);
      gatev += rstd * (acc - mu * Ar) + Br;
    }
    // nonlinearity: each 8-lane group does both units' 4 gates in parallel
    const float e = expf((gi == 2 ? -2.f : -1.f) * gatev);
    const float val = (gi == 2) ? (2.f / (1.f + e) - 1.f) : (1.f / (1.f + e));
    const float i_ = __shfl(val, b8 + uh * 4 + 0, 64);
    const float f_ = __shfl(val, b8 + uh * 4 + 1, 64);
    const float tg = __shfl(val, b8 + uh * 4 + 2, 64);
    const float o_ = __shfl(val, b8 + uh * 4 + 3, 64);
    // per-lane c,h for its unit (redundant across 8-groups, consistent)
    const float cu = f_ * (c_state * dec_r) + i_ * tg;
    const float e2 = expf(-2.f * cu);
    const float th = 2.f / (1.f + e2) - 1.f;        // tanh(unclipped c)
    float hv = o_ * th + uf_r;                      // uf_r pre-scaled 1.5x
    hv = fminf(fmaxf(hv, -10.f), 10.f);
    c_state = fminf(fmaxf(cu, -10.f), 10.f);
    const float h1 = __shfl(hv, 4, 64);             // unit 2w+1's h (from lane 4)
    if (lane == 0) {
      f2 hq; hq.x = hv; hq.y = h1;
      float* dst = hn + (size_t)t * kH + j0 + 2 * wid;
      // ONE 8B publish per wave (512 transactions/step chip-wide)
      asm volatile("global_store_dwordx2 %0, %1, off sc0 sc1"
                   :: "v"(dst), "v"(hq) : "memory");
    }
    // ---- early first samples for next step's poll: issue NOW so their
    // latency overlaps operand rotate + loop back-edge + our store drain.
    if (t + 1 < kS) {
      const float* hpn = hn + (size_t)t * kH + col0;
      asm volatile("global_load_dwordx4 %0, %2, off sc0 sc1\n\t"
                   "global_load_dwordx4 %1, %2, off sc0 sc1"
                   : "=v"(qa), "=v"(qb) : "v"(hpn) : "memory");
    }
    // rotate pipelined operands (off the serial path)
    xp_r = xp_n;
    uf_r = 1.5f * uf_n;
    dec_r = expf(-dl_n * wdc);
  }
  // drain any outstanding publish store before kernel end
  asm volatile("s_waitcnt vmcnt(0)" ::: "memory");
  if (lane == 0 || lane == 4) out[kS + kH + unit] = c_state;   // c_last
}

// ---------------- final pass: out[t], h_last ----------------
__global__ __launch_bounds__(256) void final_kernel(
    const float* __restrict__ hn, const float* __restrict__ ufcW,
    const float* __restrict__ ufcb, const float* __restrict__ ln_g,
    const float* __restrict__ ln_b, float* __restrict__ out)
{
  const int t = blockIdx.x, tid = threadIdx.x;
  __shared__ float red[4][5];
  __shared__ float muv[2];
  const float4 hv = *(const float4*)(hn + (size_t)t * kH + 4 * tid);
  const float4 uw = *(const float4*)(ufcW + 4 * tid);
  const float4 g4 = *(const float4*)(ln_g + 4 * tid);
  const float4 b4 = *(const float4*)(ln_b + 4 * tid);
  float s1 = hv.x + hv.y + hv.z + hv.w;
  float s2 = hv.x * hv.x + hv.y * hv.y + hv.z * hv.z + hv.w * hv.w;
  float p  = uw.x * g4.x * hv.x + uw.y * g4.y * hv.y + uw.z * g4.z * hv.z + uw.w * g4.w * hv.w;
  float uu = uw.x * g4.x + uw.y * g4.y + uw.z * g4.z + uw.w * g4.w;
  float cc = uw.x * b4.x + uw.y * b4.y + uw.z * b4.z + uw.w * b4.w;
#pragma unroll
  for (int d = 1; d < 64; d <<= 1) {
    s1 += __shfl_xor(s1, d, 64); s2 += __shfl_xor(s2, d, 64);
    p  += __shfl_xor(p, d, 64);  uu += __shfl_xor(uu, d, 64);
    cc += __shfl_xor(cc, d, 64);
  }
  if ((tid & 63) == 0) {
    const int wv = tid >> 6;
    red[wv][0] = s1; red[wv][1] = s2; red[wv][2] = p; red[wv][3] = uu; red[wv][4] = cc;
  }
  __syncthreads();
  if (tid == 0) {
    float S1 = 0, S2 = 0, P = 0, U = 0, C = 0;
    for (int wv = 0; wv < 4; ++wv) {
      S1 += red[wv][0]; S2 += red[wv][1]; P += red[wv][2];
      U += red[wv][3];  C += red[wv][4];
    }
    const float mu = S1 * (1.f / kH);
    const float var = S2 * (1.f / kH) - mu * mu;
    const float rstd = 1.f / sqrtf(var + kLnEps);
    const float val = rstd * (P - mu * U) + C + ufcb[0];
    out[t] = 1.f / (1.f + expf(-val));
    muv[0] = mu; muv[1] = rstd;
  }
  if (t == kS - 1) {   // h_last = h_ln of final step
    __syncthreads();
    const float mu = muv[0], rstd = muv[1];
    out[kS + 4 * tid + 0] = (hv.x - mu) * rstd * g4.x + b4.x;
    out[kS + 4 * tid + 1] = (hv.y - mu) * rstd * g4.y + b4.y;
    out[kS + 4 * tid + 2] = (hv.z - mu) * rstd * g4.z + b4.z;
    out[kS + 4 * tid + 3] = (hv.w - mu) * rstd * g4.w + b4.w;
  }
}

// ---------------- launch ----------------
extern "C" void kernel_launch(void* const* d_in, const int* in_sizes, int n_in,
                              void* d_out, int out_size, void* d_ws, size_t ws_size,
                              hipStream_t stream) {
  (void)in_sizes; (void)n_in; (void)out_size; (void)ws_size;
  const float* x      = (const float*)d_in[0];
  const float* deltas = (const float*)d_in[1];
  const float* uavf   = (const float*)d_in[2];
  const float* W_ih   = (const float*)d_in[3];
  const float* W_hh   = (const float*)d_in[4];
  const float* b_ih   = (const float*)d_in[5];
  const float* b_hh   = (const float*)d_in[6];
  const float* Wd     = (const float*)d_in[7];
  const float* uavW1  = (const float*)d_in[8];
  const float* uavb1  = (const float*)d_in[9];
  const float* uavW2  = (const float*)d_in[10];
  const float* uavb2  = (const float*)d_in[11];
  const float* ufcW   = (const float*)d_in[12];
  const float* ufcb   = (const float*)d_in[13];
  const float* ln_g   = (const float*)d_in[14];
  const float* ln_b   = (const float*)d_in[15];
  float* out = (float*)d_out;

  // ws layout (floats): xpg 16777216 | uf 4194304 | hn 4194304
  float* ws = (float*)d_ws;
  float* xpg = ws;
  float* uf  = ws + 16777216;
  float* hn  = ws + 20971520;

  init_hn_kernel<<<4096, 256, 0, stream>>>((float4*)hn);
  gemm_xp_kernel<<<dim3(64, 64), 256, 0, stream>>>(x, W_ih, b_ih, b_hh, xpg);
  gemm_uf_kernel<<<dim3(64, 16), 256, 0, stream>>>(uavf, uavW1, uavb1, uavW2, uavb2, uf);
  scan_kernel<<<kNB, 256, 0, stream>>>(xpg, uf, hn, W_hh, deltas, Wd, ln_g, ln_b, out);
  final_kernel<<<kS, 256, 0, stream>>>(hn, ufcW, ufcb, ln_g, ln_b, out);
}

// Round 11
// 10482.506 us; speedup vs baseline: 1.9530x; 1.9530x over previous
//
#include <hip/hip_runtime.h>
#include <math.h>

// ---------------------------------------------------------------------------
// UAVEnhancedModel: LSTM-with-decay + per-step LayerNorm recurrence (S=4096,
// I=512, H=1024) + uav feature path + sigmoid head.
//
// FINAL (R9 config — session optimum). Measured conclusions baked in:
//   * Per-step cost (~2.46us) is a participant-independent serial fabric
//     latency: publish->LLC visibility + drained-poll discovery + barrier.
//     Halving participants (R9), publish transactions (R7/R9), or compute
//     path (R8) each changed time by ~0%. Faster sampling (R10 double-pump)
//     congests the LLC and DOUBLES time. Serial polling (R3/R7) also 2x.
//   * Agent-scope publishes cost an HBM sector-write regardless of store
//     vs atomic-swap (R6): WRITE_SIZE == publishes x 32B always.
//   * Drained single-load sc0 sc1 poll with "+v" register ties is both the
//     fastest stable discovery and the only crash-safe one (R5 lesson:
//     never leave a poll load in flight past its register's lifetime).
//
//   1) gemm_xp: x_proj = x @ W_ih^T + (b_ih+b_hh), gate-interleaved xpg[s][u][g].
//   2) gemm_uf: uf = relu(uav*W1^T + b1) @ W2^T + b2          [4096, 1024]
//   3) scan: 128 blocks x 256 threads. Block b owns units j0..j0+7
//      (XCD-chunked). Thread tid owns cols 4*tid..4*tid+3 of ALL 32 block
//      gate-rows (128 W_hh*ln_g weights in VGPRs); its polled 16B of
//      hn[t-1] is exactly its FMA operand. bfly32 value-split butterfly;
//      34 floats/wave to LDS; ONE barrier; wave w finishes units 2w,2w+1
//      and publishes ONE dwordx2. LN folded into matvec:
//      gates = xp + rstd*(acc - mu*Ar) + Br.
//   4) final: out[t] = sigmoid(ufcW @ h_ln_t + ufcb); also h_last, c_last.
// ---------------------------------------------------------------------------

constexpr int kS  = 4096;
constexpr int kI  = 512;
constexpr int kH  = 1024;
constexpr int kG4 = 4096;   // 4*kH
constexpr int kNB = 128;    // scan blocks
constexpr float kLnEps = 1e-5f;
constexpr float kWdEps = 1e-7f;
constexpr float kSent  = 1e30f;   // h clipped to [-10,10] -> unreachable

typedef float f4 __attribute__((ext_vector_type(4)));
typedef float f2 __attribute__((ext_vector_type(2)));

// ---------------- init: fill hn with sentinel ----------------
__global__ __launch_bounds__(256) void init_hn_kernel(float4* __restrict__ p) {
  const int i = blockIdx.x * 256 + threadIdx.x;   // 4096*256 float4 = S*H
  p[i] = make_float4(kSent, kSent, kSent, kSent);
}

// -------- GEMM1: xpg[s][u][g] = sum_k x[s,k]*W_ih[g*1024+u,k] + bias ------
__global__ __launch_bounds__(256) void gemm_xp_kernel(
    const float* __restrict__ A,     // x [4096,512]
    const float* __restrict__ B,     // W_ih [4096,512]
    const float* __restrict__ b_ih, const float* __restrict__ b_hh,
    float* __restrict__ C)           // xpg [4096][1024][4]
{
  __shared__ float As[32][68];
  __shared__ float Bs[32][68];
  const int bm = blockIdx.x * 64, bn = blockIdx.y * 64;
  const int tid = threadIdx.x;
  const int tx = tid & 15, ty = tid >> 4;
  float acc[4][4] = {};
  for (int k0 = 0; k0 < kI; k0 += 32) {
#pragma unroll
    for (int h = 0; h < 2; ++h) {
      const int f = tid + h * 256;
      const int row = f >> 3, c4 = (f & 7) * 4;
      const float4 a  = *(const float4*)(A + (size_t)(bm + row) * kI + k0 + c4);
      const float4 bb = *(const float4*)(B + (size_t)(bn + row) * kI + k0 + c4);
      As[c4 + 0][row] = a.x;  As[c4 + 1][row] = a.y;
      As[c4 + 2][row] = a.z;  As[c4 + 3][row] = a.w;
      Bs[c4 + 0][row] = bb.x; Bs[c4 + 1][row] = bb.y;
      Bs[c4 + 2][row] = bb.z; Bs[c4 + 3][row] = bb.w;
    }
    __syncthreads();
#pragma unroll
    for (int k = 0; k < 32; ++k) {
      const float4 a  = *(const float4*)&As[k][ty * 4];
      const float4 bb = *(const float4*)&Bs[k][tx * 4];
      const float av[4] = {a.x, a.y, a.z, a.w};
      const float bv[4] = {bb.x, bb.y, bb.z, bb.w};
#pragma unroll
      for (int i = 0; i < 4; ++i)
#pragma unroll
        for (int j = 0; j < 4; ++j) acc[i][j] += av[i] * bv[j];
    }
    __syncthreads();
  }
  const float4 bi = *(const float4*)(b_ih + bn + tx * 4);
  const float4 bh = *(const float4*)(b_hh + bn + tx * 4);
  const float bias[4] = {bi.x + bh.x, bi.y + bh.y, bi.z + bh.z, bi.w + bh.w};
  const int gate = bn >> 10;            // 64 | 1024 -> constant per block
  const int ubase = (bn & 1023) + tx * 4;
#pragma unroll
  for (int i = 0; i < 4; ++i) {
    float* dst = C + (size_t)(bm + ty * 4 + i) * kG4 + (size_t)ubase * 4 + gate;
#pragma unroll
    for (int j = 0; j < 4; ++j) dst[4 * j] = acc[i][j] + bias[j];
  }
}

// ---------------- GEMM2: uf = relu(uav*W1^T + b1) @ W2^T + b2 --------------
__global__ __launch_bounds__(256) void gemm_uf_kernel(
    const float* __restrict__ uav,
    const float* __restrict__ W1, const float* __restrict__ b1,
    const float* __restrict__ W2,
    const float* __restrict__ b2,
    float* __restrict__ C)           // uf [4096,1024]
{
  __shared__ float As[32][68];
  __shared__ float Bs[32][68];
  __shared__ float uav_s[64];
  const int bm = blockIdx.x * 64, bn = blockIdx.y * 64;
  const int tid = threadIdx.x;
  const int tx = tid & 15, ty = tid >> 4;
  if (tid < 64) uav_s[tid] = uav[bm + tid];
  __syncthreads();
  float acc[4][4] = {};
  for (int k0 = 0; k0 < kH; k0 += 32) {
#pragma unroll
    for (int h = 0; h < 2; ++h) {
      const int f = tid + h * 256;
      const int row = f >> 3, c4 = (f & 7) * 4;
      const float4 w1v = *(const float4*)(W1 + k0 + c4);
      const float4 b1v = *(const float4*)(b1 + k0 + c4);
      const float ua = uav_s[row];
      As[c4 + 0][row] = fmaxf(ua * w1v.x + b1v.x, 0.f);
      As[c4 + 1][row] = fmaxf(ua * w1v.y + b1v.y, 0.f);
      As[c4 + 2][row] = fmaxf(ua * w1v.z + b1v.z, 0.f);
      As[c4 + 3][row] = fmaxf(ua * w1v.w + b1v.w, 0.f);
      const float4 bb = *(const float4*)(W2 + (size_t)(bn + row) * kH + k0 + c4);
      Bs[c4 + 0][row] = bb.x; Bs[c4 + 1][row] = bb.y;
      Bs[c4 + 2][row] = bb.z; Bs[c4 + 3][row] = bb.w;
    }
    __syncthreads();
#pragma unroll
    for (int k = 0; k < 32; ++k) {
      const float4 a  = *(const float4*)&As[k][ty * 4];
      const float4 bb = *(const float4*)&Bs[k][tx * 4];
      const float av[4] = {a.x, a.y, a.z, a.w};
      const float bv[4] = {bb.x, bb.y, bb.z, bb.w};
#pragma unroll
      for (int i = 0; i < 4; ++i)
#pragma unroll
        for (int j = 0; j < 4; ++j) acc[i][j] += av[i] * bv[j];
    }
    __syncthreads();
  }
  const float4 b2v = *(const float4*)(b2 + bn + tx * 4);
#pragma unroll
  for (int i = 0; i < 4; ++i) {
    float4 o = make_float4(acc[i][0] + b2v.x, acc[i][1] + b2v.y,
                           acc[i][2] + b2v.z, acc[i][3] + b2v.w);
    *(float4*)(C + (size_t)(bm + ty * 4 + i) * kH + bn + tx * 4) = o;
  }
}

// ---- value-splitting butterfly: 32 per-lane partials -> every lane holds
// the wave-total of row (lane&31). 31 shfl+select+add + 1 cross-half add.
__device__ __forceinline__ void bfly32(float (&p)[32], int lane) {
#pragma unroll
  for (int k = 0; k < 16; ++k) {
    const float give = (lane & 16) ? p[k] : p[k + 16];
    const float keep = (lane & 16) ? p[k + 16] : p[k];
    p[k] = keep + __shfl_xor(give, 16, 64);
  }
#pragma unroll
  for (int k = 0; k < 8; ++k) {
    const float give = (lane & 8) ? p[k] : p[k + 8];
    const float keep = (lane & 8) ? p[k + 8] : p[k];
    p[k] = keep + __shfl_xor(give, 8, 64);
  }
#pragma unroll
  for (int k = 0; k < 4; ++k) {
    const float give = (lane & 4) ? p[k] : p[k + 4];
    const float keep = (lane & 4) ? p[k + 4] : p[k];
    p[k] = keep + __shfl_xor(give, 4, 64);
  }
#pragma unroll
  for (int k = 0; k < 2; ++k) {
    const float give = (lane & 2) ? p[k] : p[k + 2];
    const float keep = (lane & 2) ? p[k + 2] : p[k];
    p[k] = keep + __shfl_xor(give, 2, 64);
  }
  {
    const float give = (lane & 1) ? p[0] : p[1];
    const float keep = (lane & 1) ? p[1] : p[0];
    p[0] = keep + __shfl_xor(give, 1, 64);
  }
  p[0] += __shfl_xor(p[0], 32, 64);
}

// ---------------- persistent scan kernel ----------------
// Block owns 8 units j0..j0+7 (32 rows: row r <-> unit r>>2, gate r&3).
// Thread tid: cols 4*tid..4*tid+3 of all 32 rows (128 reg weights).
// Wave w finishes units 2w (lanes lr<4) and 2w+1 (lanes lr>=4), lr=lane&7.
__global__ __launch_bounds__(256, 1) void scan_kernel(
    const float* __restrict__ xpg,    // [S][H][4] ws
    const float* __restrict__ uf,     // [S,H]  ws
    float* hn,                        // [S,H]  ws (sentinel-initialized)
    const float* __restrict__ W_hh,   // [4H,H]
    const float* __restrict__ deltas, // [S]
    const float* __restrict__ Wd,     // [H]
    const float* __restrict__ ln_g,   // [H]
    const float* __restrict__ ln_b,   // [H]
    float* __restrict__ out)          // d_out (c_last slice)
{
  const int b = blockIdx.x;
  const int tid = threadIdx.x;
  const int wid = tid >> 6, lane = tid & 63;
  const int lr = lane & 7;                 // row slot within wave's 8 rows
  const int gi = lr & 3;                   // gate (i,f,g,o)
  const int uh = lr >> 2;                  // unit half (0/1)
  const int b8 = lane & ~7;
  const int j0 = (((b & 7) << 4) | (b >> 3)) << 3;   // XCD-chunked unit base
  const int unit = j0 + 2 * wid + uh;      // this lane's unit
  const int col0 = 4 * tid;                // this thread's h columns

  __shared__ float part[2][4][36];   // [buf][wave][32 rows | s1 | s2 | pad]
  __shared__ float proA[4][32], proB[4][32];

  // --- weights (scaled by ln_g) + per-row fold constants Ar, Br ---
  f4 w4[32];
  {
    float arp[32], brp[32];
    const float4 gg = *(const float4*)(ln_g + col0);
    const float4 bb = *(const float4*)(ln_b + col0);
#pragma unroll
    for (int r = 0; r < 32; ++r) {
      const int grow = (r & 3) * kH + j0 + (r >> 2);
      const float4 wv = *(const float4*)(W_hh + (size_t)grow * kH + col0);
      brp[r] = wv.x * bb.x + wv.y * bb.y + wv.z * bb.z + wv.w * bb.w;
      w4[r].x = wv.x * gg.x; w4[r].y = wv.y * gg.y;
      w4[r].z = wv.z * gg.z; w4[r].w = wv.w * gg.w;
      arp[r] = w4[r].x + w4[r].y + w4[r].z + w4[r].w;
    }
    bfly32(arp, lane);
    bfly32(brp, lane);
    if (lane < 32) { proA[wid][lane] = arp[0]; proB[wid][lane] = brp[0]; }
  }
  __syncthreads();
  const int xr = 8 * wid + lr;             // this lane's row (block-local)
  const float Ar = proA[0][xr] + proA[1][xr] + proA[2][xr] + proA[3][xr];
  const float Br = proB[0][xr] + proB[1][xr] + proB[2][xr] + proB[3][xr];

  // --- per-lane constants / pipelined operands ---
  const float wdc = fminf(fmaxf(Wd[unit], kWdEps), 10.f);
  float c_state = 0.f;
  float xp_r = xpg[(size_t)0 * kG4 + unit * 4 + gi];
  float uf_r = 1.5f * uf[(size_t)0 * kH + unit];
  float dec_r = expf(-deltas[0] * wdc);

  for (int t = 0; t < kS; ++t) {
    const int buf = t & 1;
    if (t > 0) {
      // ---- drained single-load poll of own 16B of hn[t-1] ----
      const float* hp = hn + (size_t)(t - 1) * kH + col0;
      f4 q;
      for (;;) {
        asm volatile("global_load_dwordx4 %0, %1, off sc0 sc1"
                     : "=v"(q) : "v"(hp) : "memory");
        asm volatile("s_waitcnt vmcnt(0)" : "+v"(q) :: "memory");
        if (q.x != kSent && q.y != kSent && q.z != kSent && q.w != kSent) break;
      }
      // ---- register FMA against own columns: 32 row partials ----
      float p[32];
#pragma unroll
      for (int r = 0; r < 32; ++r)
        p[r] = w4[r].x * q.x + w4[r].y * q.y + w4[r].z * q.z + w4[r].w * q.w;
      float s1 = q.x + q.y + q.z + q.w;
      float s2 = q.x * q.x + q.y * q.y + q.z * q.z + q.w * q.w;
      bfly32(p, lane);
#pragma unroll
      for (int d = 1; d < 64; d <<= 1) {
        s1 += __shfl_xor(s1, d, 64);
        s2 += __shfl_xor(s2, d, 64);
      }
      if (lane < 32)       part[buf][wid][lane] = p[0];
      else if (lane == 32) part[buf][wid][32] = s1;
      else if (lane == 33) part[buf][wid][33] = s2;
    }
    // ---- prefetch next-step operands (after poll: vmcnt stays clean) ----
    const int tn = (t + 1 < kS) ? t + 1 : t;
    const float xp_n = xpg[(size_t)tn * kG4 + unit * 4 + gi];
    const float uf_n = uf[(size_t)tn * kH + unit];
    const float dl_n = deltas[tn];
    __syncthreads();   // single barrier per step

    float gatev = xp_r;
    if (t > 0) {
      const float acc = part[buf][0][xr] + part[buf][1][xr] +
                        part[buf][2][xr] + part[buf][3][xr];
      const float S1 = part[buf][0][32] + part[buf][1][32] +
                       part[buf][2][32] + part[buf][3][32];
      const float S2 = part[buf][0][33] + part[buf][1][33] +
                       part[buf][2][33] + part[buf][3][33];
      const float mu = S1 * (1.f / kH);
      const float var = S2 * (1.f / kH) - mu * mu;
      const float rstd = 1.f / sqrtf(var + kLnEps);
      gatev += rstd * (acc - mu * Ar) + Br;
    }
    // nonlinearity: each 8-lane group does both units' 4 gates in parallel
    const float e = expf((gi == 2 ? -2.f : -1.f) * gatev);
    const float val = (gi == 2) ? (2.f / (1.f + e) - 1.f) : (1.f / (1.f + e));
    const float i_ = __shfl(val, b8 + uh * 4 + 0, 64);
    const float f_ = __shfl(val, b8 + uh * 4 + 1, 64);
    const float tg = __shfl(val, b8 + uh * 4 + 2, 64);
    const float o_ = __shfl(val, b8 + uh * 4 + 3, 64);
    // per-lane c,h for its unit (redundant across 8-groups, consistent)
    const float cu = f_ * (c_state * dec_r) + i_ * tg;
    const float e2 = expf(-2.f * cu);
    const float th = 2.f / (1.f + e2) - 1.f;        // tanh(unclipped c)
    float hv = o_ * th + uf_r;                      // uf_r pre-scaled 1.5x
    hv = fminf(fmaxf(hv, -10.f), 10.f);
    c_state = fminf(fmaxf(cu, -10.f), 10.f);
    const float h1 = __shfl(hv, 4, 64);             // unit 2w+1's h (from lane 4)
    if (lane == 0) {
      f2 hq; hq.x = hv; hq.y = h1;
      float* dst = hn + (size_t)t * kH + j0 + 2 * wid;
      // ONE 8B publish per wave (512 transactions/step chip-wide)
      asm volatile("global_store_dwordx2 %0, %1, off sc0 sc1"
                   :: "v"(dst), "v"(hq) : "memory");
    }
    // rotate pipelined operands (off the serial path)
    xp_r = xp_n;
    uf_r = 1.5f * uf_n;
    dec_r = expf(-dl_n * wdc);
  }
  if (lane == 0 || lane == 4) out[kS + kH + unit] = c_state;   // c_last
}

// ---------------- final pass: out[t], h_last ----------------
__global__ __launch_bounds__(256) void final_kernel(
    const float* __restrict__ hn, const float* __restrict__ ufcW,
    const float* __restrict__ ufcb, const float* __restrict__ ln_g,
    const float* __restrict__ ln_b, float* __restrict__ out)
{
  const int t = blockIdx.x, tid = threadIdx.x;
  __shared__ float red[4][5];
  __shared__ float muv[2];
  const float4 hv = *(const float4*)(hn + (size_t)t * kH + 4 * tid);
  const float4 uw = *(const float4*)(ufcW + 4 * tid);
  const float4 g4 = *(const float4*)(ln_g + 4 * tid);
  const float4 b4 = *(const float4*)(ln_b + 4 * tid);
  float s1 = hv.x + hv.y + hv.z + hv.w;
  float s2 = hv.x * hv.x + hv.y * hv.y + hv.z * hv.z + hv.w * hv.w;
  float p  = uw.x * g4.x * hv.x + uw.y * g4.y * hv.y + uw.z * g4.z * hv.z + uw.w * g4.w * hv.w;
  float uu = uw.x * g4.x + uw.y * g4.y + uw.z * g4.z + uw.w * g4.w;
  float cc = uw.x * b4.x + uw.y * b4.y + uw.z * b4.z + uw.w * b4.w;
#pragma unroll
  for (int d = 1; d < 64; d <<= 1) {
    s1 += __shfl_xor(s1, d, 64); s2 += __shfl_xor(s2, d, 64);
    p  += __shfl_xor(p, d, 64);  uu += __shfl_xor(uu, d, 64);
    cc += __shfl_xor(cc, d, 64);
  }
  if ((tid & 63) == 0) {
    const int wv = tid >> 6;
    red[wv][0] = s1; red[wv][1] = s2; red[wv][2] = p; red[wv][3] = uu; red[wv][4] = cc;
  }
  __syncthreads();
  if (tid == 0) {
    float S1 = 0, S2 = 0, P = 0, U = 0, C = 0;
    for (int wv = 0; wv < 4; ++wv) {
      S1 += red[wv][0]; S2 += red[wv][1]; P += red[wv][2];
      U += red[wv][3];  C += red[wv][4];
    }
    const float mu = S1 * (1.f / kH);
    const float var = S2 * (1.f / kH) - mu * mu;
    const float rstd = 1.f / sqrtf(var + kLnEps);
    const float val = rstd * (P - mu * U) + C + ufcb[0];
    out[t] = 1.f / (1.f + expf(-val));
    muv[0] = mu; muv[1] = rstd;
  }
  if (t == kS - 1) {   // h_last = h_ln of final step
    __syncthreads();
    const float mu = muv[0], rstd = muv[1];
    out[kS + 4 * tid + 0] = (hv.x - mu) * rstd * g4.x + b4.x;
    out[kS + 4 * tid + 1] = (hv.y - mu) * rstd * g4.y + b4.y;
    out[kS + 4 * tid + 2] = (hv.z - mu) * rstd * g4.z + b4.z;
    out[kS + 4 * tid + 3] = (hv.w - mu) * rstd * g4.w + b4.w;
  }
}

// ---------------- launch ----------------
extern "C" void kernel_launch(void* const* d_in, const int* in_sizes, int n_in,
                              void* d_out, int out_size, void* d_ws, size_t ws_size,
                              hipStream_t stream) {
  (void)in_sizes; (void)n_in; (void)out_size; (void)ws_size;
  const float* x      = (const float*)d_in[0];
  const float* deltas = (const float*)d_in[1];
  const float* uavf   = (const float*)d_in[2];
  const float* W_ih   = (const float*)d_in[3];
  const float* W_hh   = (const float*)d_in[4];
  const float* b_ih   = (const float*)d_in[5];
  const float* b_hh   = (const float*)d_in[6];
  const float* Wd     = (const float*)d_in[7];
  const float* uavW1  = (const float*)d_in[8];
  const float* uavb1  = (const float*)d_in[9];
  const float* uavW2  = (const float*)d_in[10];
  const float* uavb2  = (const float*)d_in[11];
  const float* ufcW   = (const float*)d_in[12];
  const float* ufcb   = (const float*)d_in[13];
  const float* ln_g   = (const float*)d_in[14];
  const float* ln_b   = (const float*)d_in[15];
  float* out = (float*)d_out;

  // ws layout (floats): xpg 16777216 | uf 4194304 | hn 4194304
  float* ws = (float*)d_ws;
  float* xpg = ws;
  float* uf  = ws + 16777216;
  float* hn  = ws + 20971520;

  init_hn_kernel<<<4096, 256, 0, stream>>>((float4*)hn);
  gemm_xp_kernel<<<dim3(64, 64), 256, 0, stream>>>(x, W_ih, b_ih, b_hh, xpg);
  gemm_uf_kernel<<<dim3(64, 16), 256, 0, stream>>>(uavf, uavW1, uavb1, uavW2, uavb2, uf);
  scan_kernel<<<kNB, 256, 0, stream>>>(xpg, uf, hn, W_hh, deltas, Wd, ln_g, ln_b, out);
  final_kernel<<<kS, 256, 0, stream>>>(hn, ufcW, ufcb, ln_g, ln_b, out);
}